// Round 8
// baseline (229.123 us; speedup 1.0000x reference)
//
#include <hip/hip_runtime.h>

#define B_ 32
#define T_ 2048
#define N_ 128
#define K_ 5
#define BN_ (B_ * N_)
#define PMAX_ 512
#define MINP_ 2

static constexpr double PI_D = 3.14159265358979323846264338327950288;
static constexpr float  S2_F = 0.70710678118654752440f;  // sqrt(1/2)

typedef float vf4 __attribute__((ext_vector_type(4)));

struct cf { float r, i; };

__device__ __forceinline__ void bf_w(cf& u, cf& v, float wr, float wi) {
    const float tr = v.r * wr - v.i * wi;
    const float ti = v.r * wi + v.i * wr;
    v.r = u.r - tr; v.i = u.i - ti;
    u.r += tr;      u.i += ti;
}
__device__ __forceinline__ void bf_1(cf& u, cf& v) {        // w = 1
    const float tr = v.r, ti = v.i;
    v.r = u.r - tr; v.i = u.i - ti;
    u.r += tr;      u.i += ti;
}
__device__ __forceinline__ void bf_mi(cf& u, cf& v) {       // w = -i
    const float tr = v.i, ti = -v.r;
    v.r = u.r - tr; v.i = u.i - ti;
    u.r += tr;      u.i += ti;
}
// Element-index swizzle for the float2 (b64) FFT array: XOR bits 5-8 into
// bits 1-4. Keeps bit 0 -> preserves pair contiguity (b128-fusable), and
// spreads strided rounds (h=8/64/512) to min bank multiplicity.
__device__ __forceinline__ int esw(int i) { return i ^ (((i >> 5) & 15) << 1); }

// ---------------------------------------------------------------------------
// Kernel 0: twiddle table tw[m] = exp(-2*pi*i*m/2048) as float2, into d_ws.
// ---------------------------------------------------------------------------
__global__ __launch_bounds__(256) void pt_twiddle(float2* __restrict__ tw) {
    const int m = blockIdx.x * 256 + threadIdx.x;
    if (m < 1024) {
        double s, c;
        sincos(-2.0 * PI_D * (double)m / 2048.0, &s, &c);
        tw[m] = make_float2((float)c, (float)s);
    }
}

// ---------------------------------------------------------------------------
// v8 = R4 (best, 217.3) with the LDS recut:
//  - re/im interleaved as ONE float2 array Zc (b64 ops, ~40% fewer LDS
//    cycles in the FFT) with esw() bank swizzle (hand-checked min-multiplicity
//    for all round strides).
//  - Mag phase fused read-compute-write, NO barriers/staging: slot k in
//    [1..1024] is written only by the thread that reads it as pk; pn slots
//    [1024..2047] are read-only. (9 -> 8 barriers.)
//  - Everything else byte-identical in behavior to R4: pair rFFT trick,
//    register-carried seq (16 VGPR), wave-register top-5, shifted-f4 +
//    masked regular f4 store phase.
// ---------------------------------------------------------------------------
__global__ __launch_bounds__(256, 7) void pt_fft_tiles(const float* __restrict__ x,
                                                       float* __restrict__ out,
                                                       const float2* __restrict__ tw) {
    __shared__ __align__(16) float2 Zc[2052];   // FFT z / mags; later seqA|seqB
    __shared__ int sh_take[2][K_];
    float* Zf = (float*)Zc;                     // 4104 floats

    // XCD-aware swizzle (bijective on 2048 blocks): blocks with equal
    // (blockIdx & 7) (likely same XCD) get consecutive q -> adjacent x cols.
    const int i0  = blockIdx.x;
    const int q   = ((i0 & 7) << 8) | (i0 >> 3);
    const int bn0 = q * 2;
    const int b   = bn0 >> 7;          // / N_
    const int n   = bn0 & 127;         // even
    const int tid = threadIdx.x;

    // ---- Load x columns (n, n+1): z[t] = A[t] + i*B[t], bit-reversed pack.
    // sv[] (16 VGPR) carries both sequences to the store phase.
    const float* xp = x + (size_t)b * T_ * N_ + n;
    float2 sv[8];
#pragma unroll
    for (int m = 0; m < 8; ++m)
        sv[m] = *(const float2*)(xp + (size_t)(tid + 256 * m) * N_);
#pragma unroll
    for (int m = 0; m < 8; ++m) {
        const int t = tid + 256 * m;
        Zc[esw((int)(__brev((unsigned)t) >> 21))] = sv[m];   // rev11(t)
    }
    __syncthreads();

    // ---- Round 1: radix-8 (stages 1-3), h=1, constant twiddles.
    {
        const int base = tid * 8;
        cf E[8];
#pragma unroll
        for (int j = 0; j < 8; ++j) { const float2 z = Zc[esw(base + j)]; E[j].r = z.x; E[j].i = z.y; }
        bf_1(E[0], E[1]); bf_1(E[2], E[3]); bf_1(E[4], E[5]); bf_1(E[6], E[7]);
        bf_1(E[0], E[2]); bf_mi(E[1], E[3]); bf_1(E[4], E[6]); bf_mi(E[5], E[7]);
        bf_1(E[0], E[4]); bf_w(E[1], E[5], S2_F, -S2_F);
        bf_mi(E[2], E[6]); bf_w(E[3], E[7], -S2_F, -S2_F);
#pragma unroll
        for (int j = 0; j < 8; ++j) Zc[esw(base + j)] = make_float2(E[j].r, E[j].i);
    }
    __syncthreads();

    // ---- Rounds 2,3: radix-8 at stages s=4 (h=8) and s=7 (h=64).
#pragma unroll
    for (int r = 0; r < 2; ++r) {
        const int s    = 4 + 3 * r;
        const int h    = 1 << (s - 1);
        const int bq   = tid & (h - 1);
        const int g    = tid >> (s - 1);
        const int base = g * 8 * h + bq;
        const float2 w1  = tw[bq << (11 - s)];
        const float2 w2a = tw[bq << (10 - s)];
        const float2 w2b = tw[(bq + h) << (10 - s)];
        const float2 w30 = tw[bq << (9 - s)];
        const float2 w31 = tw[(bq + h) << (9 - s)];
        const float2 w32 = tw[(bq + 2 * h) << (9 - s)];
        const float2 w33 = tw[(bq + 3 * h) << (9 - s)];
        cf E[8];
#pragma unroll
        for (int j = 0; j < 8; ++j) { const float2 z = Zc[esw(base + j * h)]; E[j].r = z.x; E[j].i = z.y; }
        bf_w(E[0], E[1], w1.x, w1.y);   bf_w(E[2], E[3], w1.x, w1.y);
        bf_w(E[4], E[5], w1.x, w1.y);   bf_w(E[6], E[7], w1.x, w1.y);
        bf_w(E[0], E[2], w2a.x, w2a.y); bf_w(E[1], E[3], w2b.x, w2b.y);
        bf_w(E[4], E[6], w2a.x, w2a.y); bf_w(E[5], E[7], w2b.x, w2b.y);
        bf_w(E[0], E[4], w30.x, w30.y); bf_w(E[1], E[5], w31.x, w31.y);
        bf_w(E[2], E[6], w32.x, w32.y); bf_w(E[3], E[7], w33.x, w33.y);
#pragma unroll
        for (int j = 0; j < 8; ++j) Zc[esw(base + j * h)] = make_float2(E[j].r, E[j].i);
        __syncthreads();
    }

    // ---- Round 4: radix-4 (stages 10-11), h=512, 2 butterflies/thread.
#pragma unroll
    for (int u = 0; u < 2; ++u) {
        const int bb = tid + 256 * u;
        const float2 wA = tw[bb << 1];
        const float2 wB = tw[bb];
        const float2 wC = tw[bb + 512];
        const int p0 = esw(bb), p1 = esw(bb + 512), p2 = esw(bb + 1024), p3 = esw(bb + 1536);
        const float2 z0 = Zc[p0], z1 = Zc[p1], z2 = Zc[p2], z3 = Zc[p3];
        cf E0 = {z0.x, z0.y}, E1 = {z1.x, z1.y};
        cf E2 = {z2.x, z2.y}, E3 = {z3.x, z3.y};
        bf_w(E0, E1, wA.x, wA.y); bf_w(E2, E3, wA.x, wA.y);
        bf_w(E0, E2, wB.x, wB.y); bf_w(E1, E3, wC.x, wC.y);
        Zc[p0] = make_float2(E0.r, E0.i); Zc[p1] = make_float2(E1.r, E1.i);
        Zc[p2] = make_float2(E2.r, E2.i); Zc[p3] = make_float2(E3.r, E3.i);
    }
    __syncthreads();

    // ---- Unpack both spectra; 4*mag^2, FUSED read-compute-write (no
    // barrier needed: slot k in [1..1024] is read (pk) only by its writer;
    // pn slots [1024..2047] are never written; slot 1024 is self-paired).
#pragma unroll
    for (int m = 0; m < 4; ++m) {
        const int k  = 1 + tid + 256 * m;          // 1..1024
        const int nk = 2048 - k;
        const int pk = esw(k), pn = esw(nk);
        const float2 z = Zc[pk];
        const float2 y = Zc[pn];
        const float ar = z.x + y.x, ai = z.y - y.y;
        const float br = z.y + y.y, bi = y.x - z.x;
        Zc[pk] = make_float2(ar * ar + ai * ai, br * br + bi * bi);
    }
    __syncthreads();

    // ---- Top-5, intra-wave + register-resident: wave0 -> A (.x), wave1 -> B (.y).
    // 16 bins/lane; zero barriers, register exclusion.
    const int wid  = tid >> 6;
    const int lane = tid & 63;
    if (wid < 2) {
        float mv[16];
#pragma unroll
        for (int j = 0; j < 16; ++j) {
            const float2 mg = Zc[esw(1 + lane + 64 * j)];
            mv[j] = wid ? mg.y : mg.x;
        }
        for (int it = 0; it < K_; ++it) {
            float bestv = -2.0f;
            int   besti = 1 << 30;
#pragma unroll
            for (int j = 0; j < 16; ++j) {
                const int k = 1 + lane + 64 * j;
                if (mv[j] > bestv || (mv[j] == bestv && k < besti)) { bestv = mv[j]; besti = k; }
            }
#pragma unroll
            for (int off = 32; off > 0; off >>= 1) {
                const float v3 = __shfl_down(bestv, off);
                const int   i3 = __shfl_down(besti, off);
                if (v3 > bestv || (v3 == bestv && i3 < besti)) { bestv = v3; besti = i3; }
            }
            const int win = __shfl(besti, 0);      // broadcast winner index
#pragma unroll
            for (int j = 0; j < 16; ++j)
                if (1 + lane + 64 * j == win) mv[j] = -1.0f;   // exclude
            if (lane == 0) {
                int period = T_ / win;
                if (period > PMAX_) period = PMAX_;
                if (period < MINP_) period = MINP_;
                const int cyc = T_ / period;
                sh_take[wid][it] = (period << 16) | (period * cyc); // pack period|take
            }
        }
    }
    __syncthreads();

    // ---- periods / cycles (ints as float32).
    const size_t TILES = (size_t)BN_ * K_ * T_;
    if (tid < 2 * K_) {
        const int s2 = tid / K_, k2 = tid % K_;
        const int pk   = sh_take[s2][k2];
        const int per  = pk >> 16;
        const int take = pk & 0xFFFF;
        out[TILES + (size_t)(bn0 + s2) * K_ + k2]                      = (float)per;
        out[TILES + (size_t)BN_ * K_ + (size_t)(bn0 + s2) * K_ + k2]   = (float)(take / per);
    }

    // ---- Restore sequences linearly: seqA = Zf[0..2047] (+4 slack),
    // seqB = Zf[2052..4099] (+4 slack) from registers; mags are dead.
#pragma unroll
    for (int m = 0; m < 8; ++m) {
        const int t = tid + 256 * m;
        Zf[t]        = sv[m].x;
        Zf[2052 + t] = sv[m].y;
    }
    __syncthreads();

    // ---- Tile rows: aligned f4 LDS reads + register shift, REGULAR aligned
    // float4 stores (same shape as the 6.5 TB/s fill kernel).
    float* rowA = out + (size_t)bn0 * (K_ * T_);
#pragma unroll
    for (int m = 0; m < 20; ++m) {
        const int e  = tid + 256 * m;
        const int s2 = (e >= K_ * (T_ / 4)) ? 1 : 0;
        const int w  = e - s2 * (K_ * (T_ / 4));
        const int k  = w >> 9;                     // / 512
        const int p4 = (w & 511) << 2;
        const int take  = sh_take[s2][k] & 0xFFFF;
        const int start = T_ - take;
        const vf4* sq4 = (const vf4*)(s2 ? (Zf + 2052) : Zf);
        const int idx = start + p4;
        int a0 = idx >> 2;
        if (a0 > 511) a0 = 511;                    // clamp (masked anyway)
        const int sh = idx & 3;
        const vf4 lo = sq4[a0];
        const vf4 hi = sq4[a0 + 1];                // slack floats, masked if OOR
        float r0, r1, r2, r3;
        if (sh == 0)      { r0 = lo.x; r1 = lo.y; r2 = lo.z; r3 = lo.w; }
        else if (sh == 1) { r0 = lo.y; r1 = lo.z; r2 = lo.w; r3 = hi.x; }
        else if (sh == 2) { r0 = lo.z; r1 = lo.w; r2 = hi.x; r3 = hi.y; }
        else              { r0 = lo.w; r1 = hi.x; r2 = hi.y; r3 = hi.z; }
        vf4 vv;
        vv.x = (p4 + 0 < take) ? r0 : 0.0f;
        vv.y = (p4 + 1 < take) ? r1 : 0.0f;
        vv.z = (p4 + 2 < take) ? r2 : 0.0f;
        vv.w = (p4 + 3 < take) ? r3 : 0.0f;
        *(vf4*)(rowA + (size_t)(s2 * K_ + k) * T_ + p4) = vv;
    }
}

// ---------------------------------------------------------------------------
extern "C" void kernel_launch(void* const* d_in, const int* in_sizes, int n_in,
                              void* d_out, int out_size, void* d_ws, size_t ws_size,
                              hipStream_t stream) {
    const float* x = (const float*)d_in[0];
    float* out = (float*)d_out;
    float2* tw = (float2*)d_ws;   // 8 KB twiddle table

    pt_twiddle<<<dim3(4), dim3(256), 0, stream>>>(tw);
    pt_fft_tiles<<<dim3(BN_ / 2), dim3(256), 0, stream>>>(x, out, tw);
}